// Round 2
// baseline (104.169 us; speedup 1.0000x reference)
//
#include <hip/hip_runtime.h>

typedef _Float16 half2v __attribute__((ext_vector_type(2)));
typedef _Float16 half8  __attribute__((ext_vector_type(8)));
typedef float    floatx4 __attribute__((ext_vector_type(4)));

#define M_DIM 64
#define K_DIM 8192
#define N_DIM 8192
#define NT 64
#define KSB 4
// 4 waves/block, each wave owns a K-chunk of K_DIM/(KSB*4) = 512 rows.

// Pre-pass: x fp32 [64][8192] -> fp16 in ws, with per-8 k-permutation
// sigma = (0,4,1,5,2,6,3,7) to match the nibble-unpack order of B.
__global__ __launch_bounds__(256) void permute_x_kernel(
        const float* __restrict__ x, _Float16* __restrict__ xp) {
    int t = blockIdx.x * 256 + threadIdx.x;          // word index, M*K/8 total
    const float* src = x + (size_t)t * 8;
    float4 a = *(const float4*)(src);
    float4 b = *(const float4*)(src + 4);
    union { _Float16 h[8]; float4 f; } u;
    u.h[0] = (_Float16)a.x; u.h[1] = (_Float16)b.x;
    u.h[2] = (_Float16)a.y; u.h[3] = (_Float16)b.y;
    u.h[4] = (_Float16)a.z; u.h[5] = (_Float16)b.z;
    u.h[6] = (_Float16)a.w; u.h[7] = (_Float16)b.w;
    *(float4*)(xp + (size_t)t * 8) = u.f;
}

__device__ __forceinline__ half2v dq_pair(unsigned int bits, half2v sub, half2v sc) {
    union { unsigned int u; half2v h; } cv;
    cv.u = bits;
    return (cv.h - sub) * sc;      // v_pk_add_f16 + v_pk_mul_f16
}

__global__ __launch_bounds__(256, 2) void machete_mm_kernel(
        const _Float16* __restrict__ xp,
        const unsigned int* __restrict__ Bq,
        const float* __restrict__ s,
        float* __restrict__ partial) {
    // 32.5 KB: two-round reduction buffer, stride 65 breaks bank conflicts
    __shared__ float red[4][32][65];

    const int tid  = threadIdx.x;
    const int w    = tid >> 6;                       // wave 0..3 (splits K)
    const int lane = tid & 63;
    const int c    = lane & 15;                      // mfma col within tile
    const int q    = lane >> 4;                      // quad: k sub-range
    const int n0   = blockIdx.x * NT;
    const int ci   = blockIdx.y * 4 + w;             // k-chunk 0..15
    const int kb   = ci * (K_DIM / (KSB * 4));       // *512

    const int ncol = n0 + 4 * c;                     // 4 consecutive cols

    floatx4 acc[4][4];
    #pragma unroll
    for (int i = 0; i < 4; ++i)
        #pragma unroll
        for (int j = 0; j < 4; ++j) acc[i][j] = (floatx4)0.0f;

    // Preload all 4 scale groups for this k-chunk (independent of main loop)
    const half2v c1032 = { (_Float16)1032.0f, (_Float16)1032.0f };
    half2v s2g[4][4];
    #pragma unroll
    for (int g = 0; g < 4; ++g) {
        const float4 s4 = *(const float4*)(s + (size_t)((kb >> 7) + g) * N_DIM + ncol);
        s2g[g][0] = (half2v){ (_Float16)s4.x, (_Float16)s4.x };
        s2g[g][1] = (half2v){ (_Float16)s4.y, (_Float16)s4.y };
        s2g[g][2] = (half2v){ (_Float16)s4.z, (_Float16)s4.z };
        s2g[g][3] = (half2v){ (_Float16)s4.w, (_Float16)s4.w };
    }

    const unsigned int* bptr = Bq + (size_t)((kb >> 3) + q) * N_DIM + ncol;
    const _Float16*     aptr = xp + (size_t)c * K_DIM + kb + q * 8;

    // Explicit register pipeline: B depth-2 (HBM ~900cyc), A depth-1 (L2)
    uint4 bbuf[3];
    half8 abuf[2][4];
    bbuf[0] = *(const uint4*)bptr; bptr += (size_t)4 * N_DIM;
    bbuf[1] = *(const uint4*)bptr; bptr += (size_t)4 * N_DIM;
    #pragma unroll
    for (int mt = 0; mt < 4; ++mt)
        abuf[0][mt] = *(const half8*)(aptr + (size_t)mt * 16 * K_DIM);

    #pragma unroll
    for (int st = 0; st < 16; ++st) {                // K-steps of 32
        if (st < 14) {
            bbuf[(st + 2) % 3] = *(const uint4*)bptr;
            bptr += (size_t)4 * N_DIM;
        }
        if (st < 15) {
            #pragma unroll
            for (int mt = 0; mt < 4; ++mt)
                abuf[(st + 1) & 1][mt] =
                    *(const half8*)(aptr + 32 + (size_t)mt * 16 * K_DIM);
        }

        union { uint4 v; unsigned int a[4]; } bv;
        bv.v = bbuf[st % 3];
        const int g = st >> 2;

        #pragma unroll
        for (int t = 0; t < 4; ++t) {
            const unsigned int wd = bv.a[t];
            const half2v sc = s2g[g][t];
            union { half2v h2[4]; half8 h8; } bf;
            bf.h2[0] = dq_pair(( wd        & 0x000F000Fu) | 0x64006400u, c1032, sc);
            bf.h2[1] = dq_pair(((wd >> 4)  & 0x000F000Fu) | 0x64006400u, c1032, sc);
            bf.h2[2] = dq_pair(((wd >> 8)  & 0x000F000Fu) | 0x64006400u, c1032, sc);
            bf.h2[3] = dq_pair(((wd >> 12) & 0x000F000Fu) | 0x64006400u, c1032, sc);
            #pragma unroll
            for (int mt = 0; mt < 4; ++mt)
                acc[mt][t] = __builtin_amdgcn_mfma_f32_16x16x32_f16(
                    abuf[st & 1][mt], bf.h8, acc[mt][t], 0, 0, 0);
        }
        aptr += 32;
    }

    // Cross-wave (within-block K-split) reduction, two rounds of 32 m-rows.
    // Block's private fp32 partial tile -> ws; no atomics, no global memset.
    float* ptile = partial + ((size_t)blockIdx.y * M_DIM) * N_DIM + n0;
    #pragma unroll
    for (int r = 0; r < 2; ++r) {
        if (r) __syncthreads();                      // protect red reuse
        #pragma unroll
        for (int h = 0; h < 2; ++h) {                // mt = 2r+h
            const int mt = 2 * r + h;
            #pragma unroll
            for (int t = 0; t < 4; ++t)
                #pragma unroll
                for (int rr = 0; rr < 4; ++rr)
                    red[w][h * 16 + q * 4 + rr][4 * c + t] = acc[mt][t][rr];
        }
        __syncthreads();
        #pragma unroll
        for (int i = 0; i < 8; ++i) {
            const int idx = i * 256 + tid;           // 0..2047
            const int mr  = idx >> 6;                // 0..31
            const int nl  = idx & 63;
            const float v = red[0][mr][nl] + red[1][mr][nl]
                          + red[2][mr][nl] + red[3][mr][nl];
            ptile[(size_t)(r * 32 + mr) * N_DIM + nl] = v;
        }
    }
}

__global__ __launch_bounds__(256) void reduce_kernel(
        const float* __restrict__ partial, float* __restrict__ out) {
    const size_t i = ((size_t)blockIdx.x * 256 + threadIdx.x) * 4;
    const size_t S = (size_t)M_DIM * N_DIM;
    float4 v = *(const float4*)(partial + i);
    #pragma unroll
    for (int bk = 1; bk < KSB; ++bk) {
        const float4 u = *(const float4*)(partial + bk * S + i);
        v.x += u.x; v.y += u.y; v.z += u.z; v.w += u.w;
    }
    *(float4*)(out + i) = v;
}

extern "C" void kernel_launch(void* const* d_in, const int* in_sizes, int n_in,
                              void* d_out, int out_size, void* d_ws, size_t ws_size,
                              hipStream_t stream) {
    const float*        x  = (const float*)d_in[0];
    const unsigned int* Bq = (const unsigned int*)d_in[1];
    const float*        sc = (const float*)d_in[2];
    float* out     = (float*)d_out;
    _Float16* xp   = (_Float16*)d_ws;                        // 1 MB
    float* partial = (float*)((char*)d_ws + (1 << 20));      // KSB*2MB = 8 MB

    permute_x_kernel<<<dim3((M_DIM * K_DIM / 8) / 256), 256, 0, stream>>>(x, xp);
    machete_mm_kernel<<<dim3(N_DIM / NT, KSB), 256, 0, stream>>>(xp, Bq, sc, partial);
    reduce_kernel<<<dim3(M_DIM * N_DIM / (256 * 4)), 256, 0, stream>>>(partial, out);
}

// Round 3
// 100.422 us; speedup vs baseline: 1.0373x; 1.0373x over previous
//
#include <hip/hip_runtime.h>

typedef _Float16 half2v __attribute__((ext_vector_type(2)));
typedef _Float16 half8  __attribute__((ext_vector_type(8)));
typedef float    floatx4 __attribute__((ext_vector_type(4)));

#define M_DIM 64
#define K_DIM 8192
#define N_DIM 8192
#define NT 64
#define KSB 8
#define CHUNK (K_DIM / (KSB * 4))   // 256 k-rows per wave
#define STEPS (CHUNK / 32)          // 8 MFMA K-steps per wave

// x fp32 [64][8192] -> xp2 fp16 tiled [k/32][mt:4][q:4][c:16][j:8]
// so that each A-fragment load in mm is one contiguous 1KB wave read.
// j-order within each 8 is sigma=(0,4,1,5,2,6,3,7) matching B nibble unpack.
__global__ __launch_bounds__(256) void permute_x_kernel(
        const float* __restrict__ x, _Float16* __restrict__ xp) {
    const int t  = blockIdx.x * 256 + threadIdx.x;  // 65536 threads
    const int c  = t & 15;
    const int q  = (t >> 4) & 3;
    const int mt = (t >> 6) & 3;
    const int kb = t >> 8;                          // k/32 block, 0..255
    const int m  = mt * 16 + c;
    const int k0 = kb * 32 + q * 8;
    const float* src = x + (size_t)m * K_DIM + k0;
    float4 a = *(const float4*)(src);
    float4 b = *(const float4*)(src + 4);
    union { _Float16 h[8]; float4 f; } u;
    u.h[0] = (_Float16)a.x; u.h[1] = (_Float16)b.x;
    u.h[2] = (_Float16)a.y; u.h[3] = (_Float16)b.y;
    u.h[4] = (_Float16)a.z; u.h[5] = (_Float16)b.z;
    u.h[6] = (_Float16)a.w; u.h[7] = (_Float16)b.w;
    *(float4*)(xp + (size_t)t * 8) = u.f;
}

__device__ __forceinline__ half2v dq_pair(unsigned int bits, half2v sub, half2v sc) {
    union { unsigned int u; half2v h; } cv;
    cv.u = bits;
    return (cv.h - sub) * sc;      // v_pk_add_f16 + v_pk_mul_f16
}

__global__ __launch_bounds__(256, 3) void machete_mm_kernel(
        const _Float16* __restrict__ xp,
        const unsigned int* __restrict__ Bq,
        const float* __restrict__ s,
        float* __restrict__ partial) {
    __shared__ float red[4][32][65];                 // 32.5 KB, padded stride

    const int tid  = threadIdx.x;
    const int w    = tid >> 6;                       // wave 0..3 (splits K)
    const int lane = tid & 63;
    const int c    = lane & 15;                      // mfma col within tile
    const int q    = lane >> 4;
    const int n0   = blockIdx.x * NT;
    const int ci   = blockIdx.y * 4 + w;             // k-chunk 0..31
    const int kb   = ci * CHUNK;
    const int ncol = n0 + 4 * c;

    floatx4 acc[4][4];
    #pragma unroll
    for (int i = 0; i < 4; ++i)
        #pragma unroll
        for (int j = 0; j < 4; ++j) acc[i][j] = (floatx4)0.0f;

    // 2 scale groups per 256-k chunk
    const half2v c1032 = { (_Float16)1032.0f, (_Float16)1032.0f };
    half2v s2g[2][4];
    #pragma unroll
    for (int g = 0; g < 2; ++g) {
        const float4 s4 = *(const float4*)(s + (size_t)((kb >> 7) + g) * N_DIM + ncol);
        s2g[g][0] = (half2v){ (_Float16)s4.x, (_Float16)s4.x };
        s2g[g][1] = (half2v){ (_Float16)s4.y, (_Float16)s4.y };
        s2g[g][2] = (half2v){ (_Float16)s4.z, (_Float16)s4.z };
        s2g[g][3] = (half2v){ (_Float16)s4.w, (_Float16)s4.w };
    }

    const unsigned int* bq = Bq + (size_t)((kb >> 3) + q) * N_DIM + ncol;
    const _Float16*     ap = xp + (size_t)(kb >> 5) * 2048 + lane * 8;

    // Pipeline: B depth-2 (HBM), A depth-1 (L2), parity buffers only.
    uint4 bbuf[2];
    half8 abuf[2][4];
    bbuf[0] = *(const uint4*)bq; bq += (size_t)4 * N_DIM;
    bbuf[1] = *(const uint4*)bq; bq += (size_t)4 * N_DIM;
    #pragma unroll
    for (int mt = 0; mt < 4; ++mt)
        abuf[0][mt] = *(const half8*)(ap + mt * 512);

    #pragma unroll 2
    for (int st = 0; st < STEPS; ++st) {
        const int p = st & 1;
        const int g = st >> 2;

        // Unpack B for this step FIRST (frees bbuf[p] for the depth-2 refill).
        union { uint4 v; unsigned int a[4]; } bv;
        bv.v = bbuf[p];
        half8 bf[4];
        #pragma unroll
        for (int t = 0; t < 4; ++t) {
            const unsigned int wd = bv.a[t];
            const half2v sc = s2g[g][t];
            union { half2v h2[4]; half8 h8; } b8;
            b8.h2[0] = dq_pair(( wd        & 0x000F000Fu) | 0x64006400u, c1032, sc);
            b8.h2[1] = dq_pair(((wd >> 4)  & 0x000F000Fu) | 0x64006400u, c1032, sc);
            b8.h2[2] = dq_pair(((wd >> 8)  & 0x000F000Fu) | 0x64006400u, c1032, sc);
            b8.h2[3] = dq_pair(((wd >> 12) & 0x000F000Fu) | 0x64006400u, c1032, sc);
            bf[t] = b8.h8;
        }

        if (st < STEPS - 2) bbuf[p] = *(const uint4*)bq;   // B for st+2
        bq += (size_t)4 * N_DIM;
        if (st < STEPS - 1) {                              // A for st+1
            ap += 2048;
            #pragma unroll
            for (int mt = 0; mt < 4; ++mt)
                abuf[p ^ 1][mt] = *(const half8*)(ap + mt * 512);
        }

        #pragma unroll
        for (int t = 0; t < 4; ++t)
            #pragma unroll
            for (int mt = 0; mt < 4; ++mt)
                acc[mt][t] = __builtin_amdgcn_mfma_f32_16x16x32_f16(
                    abuf[p][mt], bf[t], acc[mt][t], 0, 0, 0);
    }

    // Cross-wave K reduction in LDS (two rounds of 32 m-rows), then one
    // coalesced fp32 partial-tile store per block. No atomics.
    float* ptile = partial + ((size_t)blockIdx.y * M_DIM) * N_DIM + n0;
    #pragma unroll
    for (int r = 0; r < 2; ++r) {
        if (r) __syncthreads();
        #pragma unroll
        for (int h = 0; h < 2; ++h) {
            const int mt = 2 * r + h;
            #pragma unroll
            for (int t = 0; t < 4; ++t)
                #pragma unroll
                for (int rr = 0; rr < 4; ++rr)
                    red[w][h * 16 + q * 4 + rr][4 * c + t] = acc[mt][t][rr];
        }
        __syncthreads();
        #pragma unroll
        for (int i = 0; i < 8; ++i) {
            const int idx = i * 256 + tid;
            const int mr  = idx >> 6;
            const int nl  = idx & 63;
            const float v = red[0][mr][nl] + red[1][mr][nl]
                          + red[2][mr][nl] + red[3][mr][nl];
            ptile[(size_t)(r * 32 + mr) * N_DIM + nl] = v;
        }
    }
}

__global__ __launch_bounds__(256) void reduce_kernel(
        const float* __restrict__ partial, float* __restrict__ out) {
    const size_t i = ((size_t)blockIdx.x * 256 + threadIdx.x) * 4;
    const size_t S = (size_t)M_DIM * N_DIM;
    float4 v = *(const float4*)(partial + i);
    #pragma unroll
    for (int bk = 1; bk < KSB; ++bk) {
        const float4 u = *(const float4*)(partial + bk * S + i);
        v.x += u.x; v.y += u.y; v.z += u.z; v.w += u.w;
    }
    *(float4*)(out + i) = v;
}

extern "C" void kernel_launch(void* const* d_in, const int* in_sizes, int n_in,
                              void* d_out, int out_size, void* d_ws, size_t ws_size,
                              hipStream_t stream) {
    const float*        x  = (const float*)d_in[0];
    const unsigned int* Bq = (const unsigned int*)d_in[1];
    const float*        sc = (const float*)d_in[2];
    float* out     = (float*)d_out;
    _Float16* xp   = (_Float16*)d_ws;                        // 1 MB
    float* partial = (float*)((char*)d_ws + (1 << 20));      // KSB*2MB = 16 MB

    permute_x_kernel<<<dim3(M_DIM * K_DIM / 8 / 256), 256, 0, stream>>>(x, xp);
    machete_mm_kernel<<<dim3(N_DIM / NT, KSB), 256, 0, stream>>>(xp, Bq, sc, partial);
    reduce_kernel<<<dim3(M_DIM * N_DIM / (256 * 4)), 256, 0, stream>>>(partial, out);
}